// Round 8
// baseline (1074.650 us; speedup 1.0000x reference)
//
#include <hip/hip_runtime.h>
#include <math.h>

#define NN 100000
#define NE 1600000
#define NG 1000
#define BN_EPS 1e-5f
#define SLC 4        // feature slices (one per XCD pair); 3.2MB slice fits 4MB L2
#define FPS 16       // features per slice
#define GBLK 512     // blocks per slice in k_gather
#define NW2 (GBLK * 4)   // 2048 waves per slice
#define CAP2 1024    // per-wave LDS index cache; balanced waves ~781 edges
#define GEMM_BLOCKS 2048
#define RNG 500
#define NBUK 200
#define BB 512
#define BCAP 12288

typedef unsigned short ushort_t;
typedef unsigned int uint_t;

__device__ inline float bf2f(ushort_t u) {
    return __uint_as_float(((uint_t)u) << 16);
}
__device__ inline ushort_t f2bf(float f) {
    uint_t u = __float_as_uint(f);
    u += 0x7FFFu + ((u >> 16) & 1u);   // RNE
    return (ushort_t)(u >> 16);
}

// ---------------- init ----------------

__global__ __launch_bounds__(256) void k_init(float* pooled, float* stats, int* bcnt) {
    int i = blockIdx.x * blockDim.x + threadIdx.x;
    int stride = gridDim.x * blockDim.x;
    for (int j = i; j < 5 * NG * 64; j += stride) pooled[j] = 0.f;
    for (int j = i; j < 1024; j += stride) stats[j] = 0.f;
    for (int j = i; j < NBUK; j += stride) bcnt[j] = 0;
}

// feat (f32 row-major) -> hbT sliced bf16 [4][NN][16]
__global__ __launch_bounds__(256) void k_f2bf(const float4* __restrict__ x, ushort_t* __restrict__ hbT) {
    int i = blockIdx.x * blockDim.x + threadIdx.x;
    int stride = gridDim.x * blockDim.x;
    for (int q = i; q < NN * 16; q += stride) {
        int n = q >> 4;
        int fq = q & 15;            // feature quad: features fq*4..fq*4+3
        int s = fq >> 2;
        int fin = (fq & 3) * 4;
        float4 v = x[q];            // = feat[n*64 + fq*4]
        uint2 r;
        r.x = (uint_t)f2bf(v.x) | ((uint_t)f2bf(v.y) << 16);
        r.y = (uint_t)f2bf(v.z) | ((uint_t)f2bf(v.w) << 16);
        *(uint2*)(hbT + (size_t)s * NN * FPS + (size_t)n * FPS + fin) = r;
    }
}

// ---------------- CSR build: block-local counting sort ----------------

__global__ __launch_bounds__(256) void k_cnt(const int* __restrict__ dst,
                                             int* __restrict__ cmat, int* __restrict__ bcnt) {
    __shared__ int l[NBUK];
    int b = blockIdx.x;
    for (int t = threadIdx.x; t < NBUK; t += 256) l[t] = 0;
    __syncthreads();
    int per = (NE + BB - 1) / BB;
    int s = b * per, e = min(NE, s + per);
    for (int i = s + threadIdx.x; i < e; i += 256) atomicAdd(&l[dst[i] / RNG], 1);
    __syncthreads();
    for (int t = threadIdx.x; t < NBUK; t += 256) {
        cmat[b * NBUK + t] = l[t];
        if (l[t]) atomicAdd(&bcnt[t], l[t]);
    }
}

__global__ __launch_bounds__(256) void k_bucket_scan(const int* __restrict__ bcnt,
                                                     int* __restrict__ boff) {
    __shared__ int s[256];
    int t = threadIdx.x;
    int v = (t < NBUK) ? bcnt[t] : 0;
    s[t] = v;
    __syncthreads();
    for (int o = 1; o < 256; o <<= 1) {
        int x = (t >= o) ? s[t - o] : 0;
        __syncthreads();
        s[t] += x;
        __syncthreads();
    }
    if (t < NBUK) boff[t] = s[t] - v;
    if (t == 0) boff[NBUK] = NE;
}

__global__ __launch_bounds__(256) void k_boffscan(const int* __restrict__ cmat,
                                                  const int* __restrict__ boff,
                                                  int* __restrict__ wmat) {
    __shared__ int s[256];
    int k = blockIdx.x;
    int t = threadIdx.x;
    int c0 = cmat[(2 * t) * NBUK + k];
    int c1 = cmat[(2 * t + 1) * NBUK + k];
    int sum = c0 + c1;
    s[t] = sum;
    __syncthreads();
    for (int o = 1; o < 256; o <<= 1) {
        int x = (t >= o) ? s[t - o] : 0;
        __syncthreads();
        s[t] += x;
        __syncthreads();
    }
    int excl = s[t] - sum + boff[k];
    wmat[(2 * t) * NBUK + k] = excl;
    wmat[(2 * t + 1) * NBUK + k] = excl + c0;
}

__global__ __launch_bounds__(256) void k_bin2(const int* __restrict__ src, const int* __restrict__ dst,
                                              const int* __restrict__ wmat, uint_t* __restrict__ binned) {
    __shared__ int l[NBUK];
    int b = blockIdx.x;
    for (int t = threadIdx.x; t < NBUK; t += 256) l[t] = 0;
    __syncthreads();
    int per = (NE + BB - 1) / BB;
    int s = b * per, e = min(NE, s + per);
    for (int i = s + threadIdx.x; i < e; i += 256) {
        int d = dst[i];
        int k = d / RNG;
        int ldst = d - k * RNG;
        int r = atomicAdd(&l[k], 1);
        binned[wmat[b * NBUK + k] + r] = ((uint_t)ldst << 17) | (uint_t)src[i];
    }
}

__global__ __launch_bounds__(256) void k_bucket_finish(
    const uint_t* __restrict__ binned, const int* __restrict__ boff,
    int* __restrict__ off, int* __restrict__ csr)
{
    __shared__ uint_t ebuf[BCAP];
    __shared__ int cnt[512];
    __shared__ int a[256];
    __shared__ int wpos[RNG];
    int k = blockIdx.x;
    int t = threadIdx.x;
    int e0 = boff[k], e1 = boff[k + 1];
    int m = e1 - e0;
    bool inl = (m <= BCAP);

    cnt[t] = 0; cnt[t + 256] = 0;
    if (inl) for (int i = t; i < m; i += 256) ebuf[i] = binned[e0 + i];
    __syncthreads();
    for (int i = t; i < m; i += 256) {
        uint_t v = inl ? ebuf[i] : binned[e0 + i];
        atomicAdd(&cnt[v >> 17], 1);
    }
    __syncthreads();
    int c0 = cnt[2 * t], c1 = cnt[2 * t + 1];
    int sum = c0 + c1;
    a[t] = sum;
    __syncthreads();
    for (int o = 1; o < 256; o <<= 1) {
        int x = (t >= o) ? a[t - o] : 0;
        __syncthreads();
        a[t] += x;
        __syncthreads();
    }
    int excl = a[t] - sum;
    int base = k * RNG;
    if (2 * t < RNG) { off[base + 2 * t] = e0 + excl; wpos[2 * t] = excl; }
    if (2 * t + 1 < RNG) { off[base + 2 * t + 1] = e0 + excl + c0; wpos[2 * t + 1] = excl + c0; }
    if (k == NBUK - 1 && t == 0) off[NN] = NE;
    __syncthreads();
    for (int i = t; i < m; i += 256) {
        uint_t v = inl ? ebuf[i] : binned[e0 + i];
        int ldst = (int)(v >> 17);
        int r = atomicAdd(&wpos[ldst], 1);
        csr[e0 + r] = (int)(v & 0x1FFFFu);
    }
}

// edge-balanced wave start nodes (per-slice wave index space, NW2 waves)
__global__ __launch_bounds__(256) void k_wstart2(const int* __restrict__ off, int* __restrict__ ws2) {
    int w = blockIdx.x * blockDim.x + threadIdx.x;
    if (w > NW2) return;
    if (w == NW2) { ws2[w] = NN; return; }
    int t = (int)(((long long)w * NE) / NW2);
    int lo = 0, hi = NN;
    while (lo < hi) { int mid = (lo + hi) >> 1; if (off[mid] < t) lo = mid + 1; else hi = mid; }
    ws2[w] = lo;
}

// ---------------- gather (feature-sliced, XCD-L2-resident) ----------------
// slice = blockIdx.x % 4  ->  lands on XCDs {s, s+4} under round-robin mapping.
// Per edge & slice: 32B gather from a 3.2MB slice array. Folds prev BN2+ReLU,
// adds self term, pools h_L, writes aggb (bf16 row-major slice columns).

template<int DORELU>
__global__ __launch_bounds__(256) void k_gather(
    const ushort_t* __restrict__ hbT,
    const float* __restrict__ st2p, const float* __restrict__ g2p, const float* __restrict__ b2p,
    const int* __restrict__ csr, const int* __restrict__ off, const int* __restrict__ ws2,
    ushort_t* __restrict__ aggb,
    const int* __restrict__ gid, float* __restrict__ poolL)
{
    __shared__ int sidx[4][CAP2];
    int lane = threadIdx.x & 63;
    int wslot = threadIdx.x >> 6;
    int s = blockIdx.x & 3;
    int w = (blockIdx.x >> 2) * 4 + wslot;
    int fl = lane & 3;          // feature quad within slice (4 bf16 = 8B)
    int grp = lane >> 2;        // 16 parallel edges

    const ushort_t* hs = hbT + (size_t)s * NN * FPS;

    float sc0 = 1.f, sc1 = 1.f, sc2 = 1.f, sc3 = 1.f;
    float sh0 = 0.f, sh1 = 0.f, sh2 = 0.f, sh3 = 0.f;
    if (DORELU) {
        int f = s * FPS + fl * 4;
#define MKCO(q, scq, shq) { \
        float mean = st2p[f + q] * (1.f / NN); \
        float var  = st2p[64 + f + q] * (1.f / NN) - mean * mean; \
        scq = rsqrtf(var + BN_EPS) * g2p[f + q]; \
        shq = b2p[f + q] - mean * scq; }
        MKCO(0, sc0, sh0) MKCO(1, sc1, sh1) MKCO(2, sc2, sh2) MKCO(3, sc3, sh3)
#undef MKCO
    }

    int n0 = ws2[w], n1 = ws2[w + 1];
    if (n0 >= n1) return;
    int e0 = off[n0], eE = off[n1];
    int lim = min(eE - e0, CAP2);
    for (int t = lane; t < lim; t += 64) sidx[wslot][t] = csr[e0 + t];

    int curg = -1;
    float p0 = 0.f, p1 = 0.f, p2 = 0.f, p3 = 0.f;

#define UNPK(p, t0, t1, t2, t3) \
    float t0 = __uint_as_float(p.x << 16); \
    float t1 = __uint_as_float(p.x & 0xFFFF0000u); \
    float t2 = __uint_as_float(p.y << 16); \
    float t3 = __uint_as_float(p.y & 0xFFFF0000u); \
    if (DORELU) { \
        t0 = fmaxf(fmaf(t0, sc0, sh0), 0.f); \
        t1 = fmaxf(fmaf(t1, sc1, sh1), 0.f); \
        t2 = fmaxf(fmaf(t2, sc2, sh2), 0.f); \
        t3 = fmaxf(fmaf(t3, sc3, sh3), 0.f); \
    }

    for (int n = n0; n < n1; ++n) {
        uint2 sp = *(const uint2*)(hs + (size_t)n * FPS + fl * 4);
        UNPK(sp, s0v, s1v, s2v, s3v)

        int g = gid[n];
        if (g != curg) {
            if (curg >= 0 && grp == 0) {
                int pb_ = curg * 64 + s * FPS + fl * 4;
                atomicAdd(&poolL[pb_], p0);
                atomicAdd(&poolL[pb_ + 1], p1);
                atomicAdd(&poolL[pb_ + 2], p2);
                atomicAdd(&poolL[pb_ + 3], p3);
            }
            curg = g; p0 = p1 = p2 = p3 = 0.f;
        }
        p0 += s0v; p1 += s1v; p2 += s2v; p3 += s3v;

        float a0 = 0.f, a1 = 0.f, a2 = 0.f, a3 = 0.f;
        int j0 = off[n] - e0, j1 = off[n + 1] - e0;
        if (j1 <= lim) {
            for (int j = j0 + grp; j < j1; j += 16) {
                int idx = sidx[wslot][j];
                uint2 q = *(const uint2*)(hs + (size_t)idx * FPS + fl * 4);
                UNPK(q, t0, t1, t2, t3)
                a0 += t0; a1 += t1; a2 += t2; a3 += t3;
            }
        } else {
            for (int j = j0 + grp; j < j1; j += 16) {
                int idx = csr[e0 + j];
                uint2 q = *(const uint2*)(hs + (size_t)idx * FPS + fl * 4);
                UNPK(q, t0, t1, t2, t3)
                a0 += t0; a1 += t1; a2 += t2; a3 += t3;
            }
        }
        a0 += __shfl_xor(a0, 4); a0 += __shfl_xor(a0, 8); a0 += __shfl_xor(a0, 16); a0 += __shfl_xor(a0, 32);
        a1 += __shfl_xor(a1, 4); a1 += __shfl_xor(a1, 8); a1 += __shfl_xor(a1, 16); a1 += __shfl_xor(a1, 32);
        a2 += __shfl_xor(a2, 4); a2 += __shfl_xor(a2, 8); a2 += __shfl_xor(a2, 16); a2 += __shfl_xor(a2, 32);
        a3 += __shfl_xor(a3, 4); a3 += __shfl_xor(a3, 8); a3 += __shfl_xor(a3, 16); a3 += __shfl_xor(a3, 32);
        if (grp == 0) {
            uint2 r;
            r.x = (uint_t)f2bf(s0v + a0) | ((uint_t)f2bf(s1v + a1) << 16);
            r.y = (uint_t)f2bf(s2v + a2) | ((uint_t)f2bf(s3v + a3) << 16);
            *(uint2*)(aggb + (size_t)n * 64 + s * FPS + fl * 4) = r;
        }
    }
    if (curg >= 0 && grp == 0) {
        int pb_ = curg * 64 + s * FPS + fl * 4;
        atomicAdd(&poolL[pb_], p0);
        atomicAdd(&poolL[pb_ + 1], p1);
        atomicAdd(&poolL[pb_ + 2], p2);
        atomicAdd(&poolL[pb_ + 3], p3);
    }
#undef UNPK
}

// ---------------- streaming GEMM (used for GEMM1 and BN1+ReLU+GEMM2) ----------------
// AFFIN: apply BN+ReLU (coefs from stIn/gIn/bIn) on input. SLOUT: write output
// in sliced layout [4][NN][16] (for next gather), else row-major [NN][64].

template<int AFFIN, int SLOUT>
__global__ __launch_bounds__(256) void k_gemm(
    const ushort_t* __restrict__ in, const float* __restrict__ stIn,
    const float* __restrict__ gIn, const float* __restrict__ bIn,
    const float* __restrict__ W, ushort_t* __restrict__ outp,
    float* __restrict__ stOut)
{
    __shared__ __align__(16) float xb[4][8][64];
    __shared__ float sred[128];
    int lane = threadIdx.x & 63;
    int wslot = threadIdx.x >> 6;
    int wid = blockIdx.x * 4 + wslot;
    int nw = GEMM_BLOCKS * 4;
    int chunk = (NN + nw - 1) / nw;
    int n0 = wid * chunk, n1 = min(NN, n0 + chunk);
    int fl = lane & 15;
    int grp = lane >> 4;

    float sq0 = 1.f, sq1 = 1.f, sq2 = 1.f, sq3 = 1.f;
    float hq0 = 0.f, hq1 = 0.f, hq2 = 0.f, hq3 = 0.f;
    float scl = 1.f, shl = 0.f;
    if (AFFIN) {
        int f = 4 * fl;
#define MKCO(q, scq, shq) { \
        float mean = stIn[f + q] * (1.f / NN); \
        float var  = stIn[64 + f + q] * (1.f / NN) - mean * mean; \
        scq = rsqrtf(var + BN_EPS) * gIn[f + q]; \
        shq = bIn[f + q] - mean * scq; }
        MKCO(0, sq0, hq0) MKCO(1, sq1, hq1) MKCO(2, sq2, hq2) MKCO(3, sq3, hq3)
#undef MKCO
        float mean = stIn[lane] * (1.f / NN);
        float var  = stIn[64 + lane] * (1.f / NN) - mean * mean;
        scl = rsqrtf(var + BN_EPS) * gIn[lane];
        shl = bIn[lane] - mean * scl;
    }

    float Wc[64];
#pragma unroll
    for (int k = 0; k < 64; k++) Wc[k] = W[k * 64 + lane];

#define STORE(nidx, val) { \
    if (SLOUT) outp[(size_t)(lane >> 4) * NN * FPS + (size_t)(nidx) * FPS + (lane & 15)] = f2bf(val); \
    else outp[(size_t)(nidx) * 64 + lane] = f2bf(val); }

    float ls = 0.f, lss = 0.f;
    if (n0 < n1) {
        int n = n0;
        for (; n + 8 <= n1; n += 8) {
            uint2 a0 = *(const uint2*)(in + ((size_t)(n + grp) << 6) + (fl << 2));
            uint2 a1 = *(const uint2*)(in + ((size_t)(n + grp + 4) << 6) + (fl << 2));
#define AFQ(p, t0, t1, t2, t3) \
            float t0 = __uint_as_float(p.x << 16); \
            float t1 = __uint_as_float(p.x & 0xFFFF0000u); \
            float t2 = __uint_as_float(p.y << 16); \
            float t3 = __uint_as_float(p.y & 0xFFFF0000u); \
            if (AFFIN) { \
                t0 = fmaxf(fmaf(t0, sq0, hq0), 0.f); \
                t1 = fmaxf(fmaf(t1, sq1, hq1), 0.f); \
                t2 = fmaxf(fmaf(t2, sq2, hq2), 0.f); \
                t3 = fmaxf(fmaf(t3, sq3, hq3), 0.f); \
            }
            { AFQ(a0, t0, t1, t2, t3)
              *(float4*)&xb[wslot][grp][4 * fl] = make_float4(t0, t1, t2, t3); }
            { AFQ(a1, t0, t1, t2, t3)
              *(float4*)&xb[wslot][grp + 4][4 * fl] = make_float4(t0, t1, t2, t3); }
#undef AFQ
#pragma unroll
            for (int r = 0; r < 8; ++r) {
                float zl = 0.f;
#pragma unroll
                for (int k = 0; k < 16; k++) {
                    float4 t4 = *(const float4*)&xb[wslot][r][k * 4];
                    zl = fmaf(t4.x, Wc[4 * k], zl);
                    zl = fmaf(t4.y, Wc[4 * k + 1], zl);
                    zl = fmaf(t4.z, Wc[4 * k + 2], zl);
                    zl = fmaf(t4.w, Wc[4 * k + 3], zl);
                }
                STORE(n + r, zl)
                ls += zl;
                lss += zl * zl;
            }
        }
        for (; n < n1; ++n) {
            float v = bf2f(in[(size_t)n * 64 + lane]);
            if (AFFIN) v = fmaxf(fmaf(v, scl, shl), 0.f);
            xb[wslot][0][lane] = v;
            float zl = 0.f;
#pragma unroll
            for (int k = 0; k < 16; k++) {
                float4 t4 = *(const float4*)&xb[wslot][0][k * 4];
                zl = fmaf(t4.x, Wc[4 * k], zl);
                zl = fmaf(t4.y, Wc[4 * k + 1], zl);
                zl = fmaf(t4.z, Wc[4 * k + 2], zl);
                zl = fmaf(t4.w, Wc[4 * k + 3], zl);
            }
            STORE(n, zl)
            ls += zl;
            lss += zl * zl;
        }
    }
#undef STORE

    if (threadIdx.x < 128) sred[threadIdx.x] = 0.f;
    __syncthreads();
    atomicAdd(&sred[lane], ls);
    atomicAdd(&sred[64 + lane], lss);
    __syncthreads();
    if (threadIdx.x < 128) atomicAdd(&stOut[threadIdx.x], sred[threadIdx.x]);
}

// final hidden rep pooling (h_4) from sliced layout

__global__ __launch_bounds__(256) void k_pool4(
    const ushort_t* __restrict__ hbT,
    const float* __restrict__ st2, const float* __restrict__ g2, const float* __restrict__ b2,
    const int* __restrict__ gid, float* __restrict__ pool)
{
    int lane = threadIdx.x & 63;
    int wslot = threadIdx.x >> 6;
    int wid = blockIdx.x * 4 + wslot;
    int nw = gridDim.x * 4;
    int chunk = (NN + nw - 1) / nw;
    int n0 = wid * chunk, n1 = min(NN, n0 + chunk);
    if (n0 >= n1) return;

    float mean = st2[lane] * (1.f / NN);
    float var  = st2[64 + lane] * (1.f / NN) - mean * mean;
    float sc = rsqrtf(var + BN_EPS) * g2[lane];
    float sh = b2[lane] - mean * sc;

    const ushort_t* hs = hbT + (size_t)(lane >> 4) * NN * FPS + (lane & 15);

    int curg = -1;
    float pacc = 0.f;
    for (int n = n0; n < n1; ++n) {
        float v = fmaxf(fmaf(bf2f(hs[(size_t)n * FPS]), sc, sh), 0.f);
        int g = gid[n];
        if (g != curg) {
            if (curg >= 0) atomicAdd(&pool[curg * 64 + lane], pacc);
            curg = g; pacc = 0.f;
        }
        pacc += v;
    }
    if (curg >= 0) atomicAdd(&pool[curg * 64 + lane], pacc);
}

// ---------------- epilogue ----------------

__global__ __launch_bounds__(256) void k_final(
    const float* __restrict__ pooled, const float* __restrict__ pW,
    const float* __restrict__ pb, float* __restrict__ out)
{
    int t = blockIdx.x * blockDim.x + threadIdx.x;
    int g = t >> 4;
    int c = t & 15;
    if (g >= NG) return;
    float acc = 0.f;
#pragma unroll
    for (int i = 0; i < 5; i++) {
        const float* P = pooled + (size_t)i * NG * 64 + g * 64;
        const float* W = pW + i * 64 * 16;
        float a = 0.f;
#pragma unroll
        for (int k = 0; k < 64; k++) a += P[k] * W[k * 16 + c];
        acc += a + pb[i * 16 + c];
    }
    float m = acc;
    for (int o = 1; o < 16; o <<= 1) m = fmaxf(m, __shfl_xor(m, o, 16));
    float e = expf(acc - m);
    float s = e;
    for (int o = 1; o < 16; o <<= 1) s += __shfl_xor(s, o, 16);
    out[g * 16 + c] = acc - m - logf(s);
}

// ---------------- launch ----------------

extern "C" void kernel_launch(void* const* d_in, const int* in_sizes, int n_in,
                              void* d_out, int out_size, void* d_ws, size_t ws_size,
                              hipStream_t stream) {
    const float* feat = (const float*)d_in[0];
    const float* W1   = (const float*)d_in[1];
    const float* W2   = (const float*)d_in[2];
    const float* bn1g = (const float*)d_in[3];
    const float* bn1b = (const float*)d_in[4];
    const float* bn2g = (const float*)d_in[5];
    const float* bn2b = (const float*)d_in[6];
    const float* pW   = (const float*)d_in[7];
    const float* pb   = (const float*)d_in[8];
    const int* src = (const int*)d_in[9];
    const int* dst = (const int*)d_in[10];
    const int* gid = (const int*)d_in[11];
    float* out = (float*)d_out;

    char* ws = (char*)d_ws;
    size_t o = 0;
    auto alloc = [&](size_t bytes) {
        void* p = ws + o;
        o += (bytes + 255) & ~(size_t)255;
        return p;
    };
    ushort_t* hbT  = (ushort_t*)alloc((size_t)NN * 64 * 2);   // sliced [4][NN][16]
    ushort_t* aggb = (ushort_t*)alloc((size_t)NN * 64 * 2);   // row-major
    ushort_t* yb   = (ushort_t*)alloc((size_t)NN * 64 * 2);   // row-major
    float* pooled = (float*)alloc((size_t)5 * NG * 64 * 4);
    float* stats  = (float*)alloc(1024 * 4);
    int* off  = (int*)alloc((size_t)(NN + 1) * 4);
    int* csr  = (int*)alloc((size_t)NE * 4);
    uint_t* binned = (uint_t*)alloc((size_t)NE * 4);
    int* cmat = (int*)alloc((size_t)BB * NBUK * 4);
    int* wmat = (int*)alloc((size_t)BB * NBUK * 4);
    int* bcnt = (int*)alloc(NBUK * 4);
    int* boff = (int*)alloc((NBUK + 1) * 4);
    int* ws2  = (int*)alloc((NW2 + 1) * 4);

    k_init<<<256, 256, 0, stream>>>(pooled, stats, bcnt);
    k_f2bf<<<1024, 256, 0, stream>>>((const float4*)feat, hbT);
    k_cnt<<<BB, 256, 0, stream>>>(dst, cmat, bcnt);
    k_bucket_scan<<<1, 256, 0, stream>>>(bcnt, boff);
    k_boffscan<<<NBUK, 256, 0, stream>>>(cmat, boff, wmat);
    k_bin2<<<BB, 256, 0, stream>>>(src, dst, wmat, binned);
    k_bucket_finish<<<NBUK, 256, 0, stream>>>(binned, boff, off, csr);
    k_wstart2<<<(NW2 + 1 + 255) / 256, 256, 0, stream>>>(off, ws2);

    for (int L = 0; L < 4; ++L) {
        float* s1 = stats + L * 256;
        float* s2 = s1 + 128;
        if (L == 0) {
            k_gather<0><<<SLC * GBLK, 256, 0, stream>>>(hbT, nullptr, nullptr, nullptr,
                                                        csr, off, ws2, aggb,
                                                        gid, pooled + (size_t)L * NG * 64);
        } else {
            k_gather<1><<<SLC * GBLK, 256, 0, stream>>>(hbT, stats + (L - 1) * 256 + 128,
                                                        bn2g + (L - 1) * 64, bn2b + (L - 1) * 64,
                                                        csr, off, ws2, aggb,
                                                        gid, pooled + (size_t)L * NG * 64);
        }
        k_gemm<0, 0><<<GEMM_BLOCKS, 256, 0, stream>>>(aggb, nullptr, nullptr, nullptr,
                                                      W1 + L * 4096, yb, s1);
        k_gemm<1, 1><<<GEMM_BLOCKS, 256, 0, stream>>>(yb, s1, bn1g + L * 64, bn1b + L * 64,
                                                      W2 + L * 4096, hbT, s2);
    }
    k_pool4<<<2048, 256, 0, stream>>>(hbT, stats + 3 * 256 + 128, bn2g + 3 * 64, bn2b + 3 * 64,
                                      gid, pooled + (size_t)4 * NG * 64);
    k_final<<<(NG * 16 + 255) / 256, 256, 0, stream>>>(pooled, pW, pb, out);
}

// Round 9
// 782.958 us; speedup vs baseline: 1.3726x; 1.3726x over previous
//
#include <hip/hip_runtime.h>
#include <math.h>

#define NN 100000
#define NE 1600000
#define NG 1000
#define BN_EPS 1e-5f
#define AGG_BLOCKS 2048
#define NWAVES (AGG_BLOCKS * 4)
#define CAP 512      // per-wave LDS index cache (ints)
#define MMAX 64      // per-wave LDS node-metadata cache (nodes); waves avg ~12 nodes
#define RNG 500
#define NBUK 200
#define BB 512
#define BCAP 12288

typedef unsigned short ushort_t;
typedef unsigned int uint_t;

__device__ inline float bf2f(ushort_t u) {
    return __uint_as_float(((uint_t)u) << 16);
}
__device__ inline ushort_t f2bf(float f) {
    uint_t u = __float_as_uint(f);
    u += 0x7FFFu + ((u >> 16) & 1u);   // RNE
    return (ushort_t)(u >> 16);
}

// ---------------- init ----------------

__global__ __launch_bounds__(256) void k_init(float* pooled, float* stats, int* bcnt) {
    int i = blockIdx.x * blockDim.x + threadIdx.x;
    int stride = gridDim.x * blockDim.x;
    for (int j = i; j < 5 * NG * 64; j += stride) pooled[j] = 0.f;
    for (int j = i; j < 1024; j += stride) stats[j] = 0.f;
    for (int j = i; j < NBUK; j += stride) bcnt[j] = 0;
}

__global__ __launch_bounds__(256) void k_f2bf(const float4* __restrict__ x, uint2* __restrict__ o) {
    int i = blockIdx.x * blockDim.x + threadIdx.x;
    int stride = gridDim.x * blockDim.x;
    for (int j = i; j < NN * 16; j += stride) {
        float4 v = x[j];
        uint2 r;
        r.x = (uint_t)f2bf(v.x) | ((uint_t)f2bf(v.y) << 16);
        r.y = (uint_t)f2bf(v.z) | ((uint_t)f2bf(v.w) << 16);
        o[j] = r;
    }
}

// ---------------- CSR build: block-local counting sort ----------------

__global__ __launch_bounds__(256) void k_cnt(const int* __restrict__ dst,
                                             int* __restrict__ cmat, int* __restrict__ bcnt) {
    __shared__ int l[NBUK];
    int b = blockIdx.x;
    for (int t = threadIdx.x; t < NBUK; t += 256) l[t] = 0;
    __syncthreads();
    int per = (NE + BB - 1) / BB;
    int s = b * per, e = min(NE, s + per);
    for (int i = s + threadIdx.x; i < e; i += 256) atomicAdd(&l[dst[i] / RNG], 1);
    __syncthreads();
    for (int t = threadIdx.x; t < NBUK; t += 256) {
        cmat[b * NBUK + t] = l[t];
        if (l[t]) atomicAdd(&bcnt[t], l[t]);
    }
}

// per-bucket column scan of cmat -> per-(block,bucket) write windows.
// Also computes boff internally (each block scans bcnt) -> one less kernel.
__global__ __launch_bounds__(256) void k_boffscan(const int* __restrict__ bcnt,
                                                  const int* __restrict__ cmat,
                                                  int* __restrict__ wmat,
                                                  int* __restrict__ boff) {
    __shared__ int sb[256];
    __shared__ int s[256];
    int k = blockIdx.x;
    int t = threadIdx.x;
    // bucket-level exclusive prefix (all blocks redo this tiny scan)
    int bv = (t < NBUK) ? bcnt[t] : 0;
    sb[t] = bv;
    __syncthreads();
    for (int o = 1; o < 256; o <<= 1) {
        int x = (t >= o) ? sb[t - o] : 0;
        __syncthreads();
        sb[t] += x;
        __syncthreads();
    }
    int boffk = sb[k] - ((k < NBUK) ? bcnt[k] : 0);   // exclusive at k
    if (t == 0) boff[k] = boffk;
    if (k == 0 && t == 0) boff[NBUK] = NE;
    // column scan over blocks for bucket k
    int c0 = cmat[(2 * t) * NBUK + k];
    int c1 = cmat[(2 * t + 1) * NBUK + k];
    int sum = c0 + c1;
    s[t] = sum;
    __syncthreads();
    for (int o = 1; o < 256; o <<= 1) {
        int x = (t >= o) ? s[t - o] : 0;
        __syncthreads();
        s[t] += x;
        __syncthreads();
    }
    int excl = s[t] - sum + boffk;
    wmat[(2 * t) * NBUK + k] = excl;
    wmat[(2 * t + 1) * NBUK + k] = excl + c0;
}

__global__ __launch_bounds__(256) void k_bin2(const int* __restrict__ src, const int* __restrict__ dst,
                                              const int* __restrict__ wmat, uint_t* __restrict__ binned) {
    __shared__ int l[NBUK];
    int b = blockIdx.x;
    for (int t = threadIdx.x; t < NBUK; t += 256) l[t] = 0;
    __syncthreads();
    int per = (NE + BB - 1) / BB;
    int s = b * per, e = min(NE, s + per);
    for (int i = s + threadIdx.x; i < e; i += 256) {
        int d = dst[i];
        int k = d / RNG;
        int ldst = d - k * RNG;
        int r = atomicAdd(&l[k], 1);
        binned[wmat[b * NBUK + k] + r] = ((uint_t)ldst << 17) | (uint_t)src[i];
    }
}

__global__ __launch_bounds__(256) void k_bucket_finish(
    const uint_t* __restrict__ binned, const int* __restrict__ boff,
    int* __restrict__ off, int* __restrict__ csr)
{
    __shared__ uint_t ebuf[BCAP];
    __shared__ int cnt[512];
    __shared__ int a[256];
    __shared__ int wpos[RNG];
    int k = blockIdx.x;
    int t = threadIdx.x;
    int e0 = boff[k], e1 = boff[k + 1];
    int m = e1 - e0;
    bool inl = (m <= BCAP);

    cnt[t] = 0; cnt[t + 256] = 0;
    if (inl) for (int i = t; i < m; i += 256) ebuf[i] = binned[e0 + i];
    __syncthreads();
    for (int i = t; i < m; i += 256) {
        uint_t v = inl ? ebuf[i] : binned[e0 + i];
        atomicAdd(&cnt[v >> 17], 1);
    }
    __syncthreads();
    int c0 = cnt[2 * t], c1 = cnt[2 * t + 1];
    int sum = c0 + c1;
    a[t] = sum;
    __syncthreads();
    for (int o = 1; o < 256; o <<= 1) {
        int x = (t >= o) ? a[t - o] : 0;
        __syncthreads();
        a[t] += x;
        __syncthreads();
    }
    int excl = a[t] - sum;
    int base = k * RNG;
    if (2 * t < RNG) { off[base + 2 * t] = e0 + excl; wpos[2 * t] = excl; }
    if (2 * t + 1 < RNG) { off[base + 2 * t + 1] = e0 + excl + c0; wpos[2 * t + 1] = excl + c0; }
    if (k == NBUK - 1 && t == 0) off[NN] = NE;
    __syncthreads();
    for (int i = t; i < m; i += 256) {
        uint_t v = inl ? ebuf[i] : binned[e0 + i];
        int ldst = (int)(v >> 17);
        int r = atomicAdd(&wpos[ldst], 1);
        csr[e0 + r] = (int)(v & 0x1FFFFu);
    }
}

// edge-balanced wave start nodes
__global__ __launch_bounds__(256) void k_wstart(const int* __restrict__ off, int* __restrict__ wstart) {
    int w = blockIdx.x * blockDim.x + threadIdx.x;
    if (w > NWAVES) return;
    if (w == NWAVES) { wstart[w] = NN; return; }
    int t = (int)(((long long)w * NE) / NWAVES);
    int lo = 0, hi = NN;
    while (lo < hi) { int mid = (lo + hi) >> 1; if (off[mid] < t) lo = mid + 1; else hi = mid; }
    wstart[w] = lo;
}

// ---------------- fused layer kernels ----------------
// k_agg (R6 shape + serial-chain fixes): quad-vectorized gather (4 neighbors
// per wave-load), folds prev BN2+ReLU, GEMM1, BN1 stats, pool of h_L.
// NEW: off[]/gid[] cached in LDS per wave; next self row prefetched in reg.

template<int DORELU>
__global__ __launch_bounds__(256) void k_agg(
    const ushort_t* __restrict__ zb,
    const float* __restrict__ stats2p, const float* __restrict__ g2p, const float* __restrict__ b2p,
    const int* __restrict__ csr, const int* __restrict__ off, const int* __restrict__ wstart,
    const float* __restrict__ W1, ushort_t* __restrict__ yb,
    float* __restrict__ stats1,
    const int* __restrict__ gid, float* __restrict__ poolL)
{
    __shared__ __align__(16) float buf[4][64];
    __shared__ int sidx[4][CAP];
    __shared__ int soff[4][MMAX + 1];
    __shared__ int sgid[4][MMAX];
    __shared__ float sred[128];
    int lane = threadIdx.x & 63;
    int wslot = threadIdx.x >> 6;
    int wid = blockIdx.x * 4 + wslot;
    int fl = lane & 15;
    int grp = lane >> 4;

    float scv0 = 1.f, scv1 = 1.f, scv2 = 1.f, scv3 = 1.f;
    float shv0 = 0.f, shv1 = 0.f, shv2 = 0.f, shv3 = 0.f;
    if (DORELU) {
        int f = 4 * fl;
#define MKCO(q, scq, shq) { \
        float mean = stats2p[f + q] * (1.f / NN); \
        float var  = stats2p[64 + f + q] * (1.f / NN) - mean * mean; \
        scq = rsqrtf(var + BN_EPS) * g2p[f + q]; \
        shq = b2p[f + q] - mean * scq; }
        MKCO(0, scv0, shv0) MKCO(1, scv1, shv1) MKCO(2, scv2, shv2) MKCO(3, scv3, shv3)
#undef MKCO
    }

    float Wc[64];
#pragma unroll
    for (int k = 0; k < 64; k++) Wc[k] = W1[k * 64 + lane];

    float ls = 0.f, lss = 0.f;

    int n0 = wstart[wid], n1 = wstart[wid + 1];

    if (n0 < n1) {
        int nn = n1 - n0;
        int e0 = off[n0];
        int eEnd = off[n1];
        int lim = min(eEnd - e0, CAP);
        // cache this wave's csr slice + node metadata in LDS
        for (int t = lane; t < lim; t += 64) sidx[wslot][t] = csr[e0 + t];
        int mcap = min(nn, MMAX);
        for (int t = lane; t < mcap + 1; t += 64) soff[wslot][t] = off[n0 + t];
        for (int t = lane; t < mcap; t += 64) sgid[wslot][t] = gid[n0 + t];

        int curg = -1;
        float p0 = 0.f, p1 = 0.f, p2 = 0.f, p3 = 0.f;

        // prefetch first self row
        uint2 sp = *(const uint2*)(zb + ((size_t)n0 << 6) + (fl << 2));

#define AFF(t, scq, shq) (DORELU ? fmaxf(fmaf(t, scq, shq), 0.f) : (t))
#define UNPK(p, t0, t1, t2, t3) \
        float t0 = AFF(__uint_as_float(p.x << 16), scv0, shv0); \
        float t1 = AFF(__uint_as_float(p.x & 0xFFFF0000u), scv1, shv1); \
        float t2 = AFF(__uint_as_float(p.y << 16), scv2, shv2); \
        float t3 = AFF(__uint_as_float(p.y & 0xFFFF0000u), scv3, shv3);

        for (int n = n0; n < n1; ++n) {
            int m = n - n0;
            int s0l, s1l, g;
            if (m < MMAX) {
                s0l = soff[wslot][m] - e0;
                s1l = soff[wslot][m + 1] - e0;
                g = sgid[wslot][m];
            } else {
                s0l = off[n] - e0;
                s1l = off[n + 1] - e0;
                g = gid[n];
            }
            uint2 spn = sp;                    // this node's self row
            if (n + 1 < n1)                    // prefetch next self row
                sp = *(const uint2*)(zb + ((size_t)(n + 1) << 6) + (fl << 2));

            // gather (issue loads ASAP; bounds came from LDS)
            float b0 = 0.f, b1 = 0.f, b2 = 0.f, b3 = 0.f;
            int j = s0l + grp;
            if (s1l <= lim) {
                for (; j + 12 < s1l; j += 16) {
                    int i0 = sidx[wslot][j], i1 = sidx[wslot][j + 4],
                        i2 = sidx[wslot][j + 8], i3 = sidx[wslot][j + 12];
                    uint2 q0 = *(const uint2*)(zb + ((size_t)i0 << 6) + (fl << 2));
                    uint2 q1 = *(const uint2*)(zb + ((size_t)i1 << 6) + (fl << 2));
                    uint2 q2 = *(const uint2*)(zb + ((size_t)i2 << 6) + (fl << 2));
                    uint2 q3 = *(const uint2*)(zb + ((size_t)i3 << 6) + (fl << 2));
                    { UNPK(q0, t0, t1, t2, t3) b0 += t0; b1 += t1; b2 += t2; b3 += t3; }
                    { UNPK(q1, t0, t1, t2, t3) b0 += t0; b1 += t1; b2 += t2; b3 += t3; }
                    { UNPK(q2, t0, t1, t2, t3) b0 += t0; b1 += t1; b2 += t2; b3 += t3; }
                    { UNPK(q3, t0, t1, t2, t3) b0 += t0; b1 += t1; b2 += t2; b3 += t3; }
                }
                for (; j < s1l; j += 4) {
                    int i0 = sidx[wslot][j];
                    uint2 q0 = *(const uint2*)(zb + ((size_t)i0 << 6) + (fl << 2));
                    UNPK(q0, t0, t1, t2, t3) b0 += t0; b1 += t1; b2 += t2; b3 += t3;
                }
            } else {
                for (; j < s1l; j += 4) {
                    int i0 = csr[e0 + j];
                    uint2 q0 = *(const uint2*)(zb + ((size_t)i0 << 6) + (fl << 2));
                    UNPK(q0, t0, t1, t2, t3) b0 += t0; b1 += t1; b2 += t2; b3 += t3;
                }
            }

            // self row + pooling (VALU; overlaps outstanding gather loads)
            UNPK(spn, s0v, s1v, s2v, s3v)
            if (g != curg) {
                if (curg >= 0 && grp == 0) {
                    atomicAdd(&poolL[curg * 64 + 4 * fl], p0);
                    atomicAdd(&poolL[curg * 64 + 4 * fl + 1], p1);
                    atomicAdd(&poolL[curg * 64 + 4 * fl + 2], p2);
                    atomicAdd(&poolL[curg * 64 + 4 * fl + 3], p3);
                }
                curg = g; p0 = p1 = p2 = p3 = 0.f;
            }
            p0 += s0v; p1 += s1v; p2 += s2v; p3 += s3v;

            // combine neighbor subsets across the 4 groups
            b0 += __shfl_xor(b0, 16); b0 += __shfl_xor(b0, 32);
            b1 += __shfl_xor(b1, 16); b1 += __shfl_xor(b1, 32);
            b2 += __shfl_xor(b2, 16); b2 += __shfl_xor(b2, 32);
            b3 += __shfl_xor(b3, 16); b3 += __shfl_xor(b3, 32);

            if (grp == 0) {
                ((float4*)buf[wslot])[fl] = make_float4(s0v + b0, s1v + b1, s2v + b2, s3v + b3);
            }
            // GEMM1: lane = output feature
            float yl = 0.f;
#pragma unroll
            for (int k = 0; k < 16; k++) {
                float4 z4 = *(const float4*)&buf[wslot][k * 4];
                yl = fmaf(z4.x, Wc[4 * k], yl);
                yl = fmaf(z4.y, Wc[4 * k + 1], yl);
                yl = fmaf(z4.z, Wc[4 * k + 2], yl);
                yl = fmaf(z4.w, Wc[4 * k + 3], yl);
            }
            yb[(size_t)n * 64 + lane] = f2bf(yl);
            ls += yl;
            lss += yl * yl;
        }
        if (curg >= 0 && grp == 0) {
            atomicAdd(&poolL[curg * 64 + 4 * fl], p0);
            atomicAdd(&poolL[curg * 64 + 4 * fl + 1], p1);
            atomicAdd(&poolL[curg * 64 + 4 * fl + 2], p2);
            atomicAdd(&poolL[curg * 64 + 4 * fl + 3], p3);
        }
#undef AFF
#undef UNPK
    }

    if (threadIdx.x < 128) sred[threadIdx.x] = 0.f;
    __syncthreads();
    atomicAdd(&sred[lane], ls);
    atomicAdd(&sred[64 + lane], lss);
    __syncthreads();
    if (threadIdx.x < 128) atomicAdd(&stats1[threadIdx.x], sred[threadIdx.x]);
}

// k_g2: BN1 apply + ReLU + GEMM2 + BN2 stats; bf16 in/out; 8-row batches,
// 8B vector loads (grp = row, fl = feature quad).

__global__ __launch_bounds__(256) void k_g2(
    const ushort_t* __restrict__ yb, const float* __restrict__ stats1,
    const float* __restrict__ g1, const float* __restrict__ b1,
    const float* __restrict__ W2, ushort_t* __restrict__ zb,
    float* __restrict__ stats2)
{
    __shared__ __align__(16) float xb[4][8][64];
    __shared__ float sred[128];
    int lane = threadIdx.x & 63;
    int wslot = threadIdx.x >> 6;
    int wid = blockIdx.x * 4 + wslot;
    int nw = AGG_BLOCKS * 4;
    int chunk = (NN + nw - 1) / nw;
    int n0 = wid * chunk, n1 = min(NN, n0 + chunk);
    int fl = lane & 15;
    int grp = lane >> 4;

    float sq0, sq1, sq2, sq3, hq0, hq1, hq2, hq3;
    {
        int f = 4 * fl;
#define MKCO(q, scq, shq) { \
        float mean = stats1[f + q] * (1.f / NN); \
        float var  = stats1[64 + f + q] * (1.f / NN) - mean * mean; \
        scq = rsqrtf(var + BN_EPS) * g1[f + q]; \
        shq = b1[f + q] - mean * scq; }
        MKCO(0, sq0, hq0) MKCO(1, sq1, hq1) MKCO(2, sq2, hq2) MKCO(3, sq3, hq3)
#undef MKCO
    }
    float scl, shl;
    {
        float mean = stats1[lane] * (1.f / NN);
        float var  = stats1[64 + lane] * (1.f / NN) - mean * mean;
        scl = rsqrtf(var + BN_EPS) * g1[lane];
        shl = b1[lane] - mean * scl;
    }

    float Wc[64];
#pragma unroll
    for (int k = 0; k < 64; k++) Wc[k] = W2[k * 64 + lane];

    float ls = 0.f, lss = 0.f;
    if (n0 < n1) {
        int n = n0;
        for (; n + 8 <= n1; n += 8) {
            uint2 a0 = *(const uint2*)(yb + ((size_t)(n + grp) << 6) + (fl << 2));
            uint2 a1 = *(const uint2*)(yb + ((size_t)(n + grp + 4) << 6) + (fl << 2));
#define AFQ(p, t0, t1, t2, t3) \
            float t0 = fmaxf(fmaf(__uint_as_float(p.x << 16), sq0, hq0), 0.f); \
            float t1 = fmaxf(fmaf(__uint_as_float(p.x & 0xFFFF0000u), sq1, hq1), 0.f); \
            float t2 = fmaxf(fmaf(__uint_as_float(p.y << 16), sq2, hq2), 0.f); \
            float t3 = fmaxf(fmaf(__uint_as_float(p.y & 0xFFFF0000u), sq3, hq3), 0.f);
            { AFQ(a0, t0, t1, t2, t3)
              *(float4*)&xb[wslot][grp][4 * fl] = make_float4(t0, t1, t2, t3); }
            { AFQ(a1, t0, t1, t2, t3)
              *(float4*)&xb[wslot][grp + 4][4 * fl] = make_float4(t0, t1, t2, t3); }
#undef AFQ
#pragma unroll
            for (int r = 0; r < 8; ++r) {
                float zl = 0.f;
#pragma unroll
                for (int k = 0; k < 16; k++) {
                    float4 t4 = *(const float4*)&xb[wslot][r][k * 4];
                    zl = fmaf(t4.x, Wc[4 * k], zl);
                    zl = fmaf(t4.y, Wc[4 * k + 1], zl);
                    zl = fmaf(t4.z, Wc[4 * k + 2], zl);
                    zl = fmaf(t4.w, Wc[4 * k + 3], zl);
                }
                zb[(size_t)(n + r) * 64 + lane] = f2bf(zl);
                ls += zl;
                lss += zl * zl;
            }
        }
        for (; n < n1; ++n) {
            float v = fmaxf(fmaf(bf2f(yb[(size_t)n * 64 + lane]), scl, shl), 0.f);
            xb[wslot][0][lane] = v;
            float zl = 0.f;
#pragma unroll
            for (int k = 0; k < 16; k++) {
                float4 t4 = *(const float4*)&xb[wslot][0][k * 4];
                zl = fmaf(t4.x, Wc[4 * k], zl);
                zl = fmaf(t4.y, Wc[4 * k + 1], zl);
                zl = fmaf(t4.z, Wc[4 * k + 2], zl);
                zl = fmaf(t4.w, Wc[4 * k + 3], zl);
            }
            zb[(size_t)n * 64 + lane] = f2bf(zl);
            ls += zl;
            lss += zl * zl;
        }
    }

    if (threadIdx.x < 128) sred[threadIdx.x] = 0.f;
    __syncthreads();
    atomicAdd(&sred[lane], ls);
    atomicAdd(&sred[64 + lane], lss);
    __syncthreads();
    if (threadIdx.x < 128) atomicAdd(&stats2[threadIdx.x], sred[threadIdx.x]);
}

// final hidden rep pooling (h_4)

__global__ __launch_bounds__(256) void k_pool4(
    const ushort_t* __restrict__ zb,
    const float* __restrict__ stats2, const float* __restrict__ g2, const float* __restrict__ b2,
    const int* __restrict__ gid, float* __restrict__ pool)
{
    int lane = threadIdx.x & 63;
    int wslot = threadIdx.x >> 6;
    int wid = blockIdx.x * 4 + wslot;
    int nw = gridDim.x * 4;
    int chunk = (NN + nw - 1) / nw;
    int n0 = wid * chunk, n1 = min(NN, n0 + chunk);
    if (n0 >= n1) return;

    float mean = stats2[lane] * (1.f / NN);
    float var  = stats2[64 + lane] * (1.f / NN) - mean * mean;
    float sc = rsqrtf(var + BN_EPS) * g2[lane];
    float sh = b2[lane] - mean * sc;

    int curg = -1;
    float pacc = 0.f;
    for (int n = n0; n < n1; ++n) {
        float v = fmaxf(fmaf(bf2f(zb[(size_t)n * 64 + lane]), sc, sh), 0.f);
        int g = gid[n];
        if (g != curg) {
            if (curg >= 0) atomicAdd(&pool[curg * 64 + lane], pacc);
            curg = g; pacc = 0.f;
        }
        pacc += v;
    }
    if (curg >= 0) atomicAdd(&pool[curg * 64 + lane], pacc);
}

// ---------------- epilogue ----------------

__global__ __launch_bounds__(256) void k_final(
    const float* __restrict__ pooled, const float* __restrict__ pW,
    const float* __restrict__ pb, float* __restrict__ out)
{
    int t = blockIdx.x * blockDim.x + threadIdx.x;
    int g = t >> 4;
    int c = t & 15;
    if (g >= NG) return;
    float acc = 0.f;
#pragma unroll
    for (int i = 0; i < 5; i++) {
        const float* P = pooled + (size_t)i * NG * 64 + g * 64;
        const float* W = pW + i * 64 * 16;
        float a = 0.f;
#pragma unroll
        for (int k = 0; k < 64; k++) a += P[k] * W[k * 16 + c];
        acc += a + pb[i * 16 + c];
    }
    float m = acc;
    for (int o = 1; o < 16; o <<= 1) m = fmaxf(m, __shfl_xor(m, o, 16));
    float e = expf(acc - m);
    float s = e;
    for (int o = 1; o < 16; o <<= 1) s += __shfl_xor(s, o, 16);
    out[g * 16 + c] = acc - m - logf(s);
}

// ---------------- launch ----------------

extern "C" void kernel_launch(void* const* d_in, const int* in_sizes, int n_in,
                              void* d_out, int out_size, void* d_ws, size_t ws_size,
                              hipStream_t stream) {
    const float* feat = (const float*)d_in[0];
    const float* W1   = (const float*)d_in[1];
    const float* W2   = (const float*)d_in[2];
    const float* bn1g = (const float*)d_in[3];
    const float* bn1b = (const float*)d_in[4];
    const float* bn2g = (const float*)d_in[5];
    const float* bn2b = (const float*)d_in[6];
    const float* pW   = (const float*)d_in[7];
    const float* pb   = (const float*)d_in[8];
    const int* src = (const int*)d_in[9];
    const int* dst = (const int*)d_in[10];
    const int* gid = (const int*)d_in[11];
    float* out = (float*)d_out;

    char* ws = (char*)d_ws;
    size_t o = 0;
    auto alloc = [&](size_t bytes) {
        void* p = ws + o;
        o += (bytes + 255) & ~(size_t)255;
        return p;
    };
    ushort_t* zb  = (ushort_t*)alloc((size_t)NN * 64 * 2);
    ushort_t* yb  = (ushort_t*)alloc((size_t)NN * 64 * 2);
    float* pooled = (float*)alloc((size_t)5 * NG * 64 * 4);
    float* stats  = (float*)alloc(1024 * 4);
    int* off  = (int*)alloc((size_t)(NN + 1) * 4);
    int* csr  = (int*)alloc((size_t)NE * 4);
    uint_t* binned = (uint_t*)alloc((size_t)NE * 4);
    int* cmat = (int*)alloc((size_t)BB * NBUK * 4);
    int* wmat = (int*)alloc((size_t)BB * NBUK * 4);
    int* bcnt = (int*)alloc(NBUK * 4);
    int* boff = (int*)alloc((NBUK + 1) * 4);
    int* wstart = (int*)alloc((NWAVES + 1) * 4);

    k_init<<<256, 256, 0, stream>>>(pooled, stats, bcnt);
    k_f2bf<<<1024, 256, 0, stream>>>((const float4*)feat, (uint2*)zb);
    k_cnt<<<BB, 256, 0, stream>>>(dst, cmat, bcnt);
    k_boffscan<<<NBUK, 256, 0, stream>>>(bcnt, cmat, wmat, boff);
    k_bin2<<<BB, 256, 0, stream>>>(src, dst, wmat, binned);
    k_bucket_finish<<<NBUK, 256, 0, stream>>>(binned, boff, off, csr);
    k_wstart<<<(NWAVES + 1 + 255) / 256, 256, 0, stream>>>(off, wstart);

    for (int L = 0; L < 4; ++L) {
        float* s1 = stats + L * 256;
        float* s2 = s1 + 128;
        if (L == 0) {
            k_agg<0><<<AGG_BLOCKS, 256, 0, stream>>>(zb, nullptr, nullptr, nullptr,
                                                     csr, off, wstart, W1 + L * 4096, yb, s1,
                                                     gid, pooled + (size_t)L * NG * 64);
        } else {
            k_agg<1><<<AGG_BLOCKS, 256, 0, stream>>>(zb, stats + (L - 1) * 256 + 128,
                                                     bn2g + (L - 1) * 64, bn2b + (L - 1) * 64,
                                                     csr, off, wstart, W1 + L * 4096, yb, s1,
                                                     gid, pooled + (size_t)L * NG * 64);
        }
        k_g2<<<AGG_BLOCKS, 256, 0, stream>>>(yb, s1, bn1g + L * 64, bn1b + L * 64,
                                             W2 + L * 4096, zb, s2);
    }
    k_pool4<<<AGG_BLOCKS, 256, 0, stream>>>(zb, stats + 3 * 256 + 128, bn2g + 3 * 64, bn2b + 3 * 64,
                                            gid, pooled + (size_t)4 * NG * 64);
    k_final<<<(NG * 16 + 255) / 256, 256, 0, stream>>>(pooled, pW, pb, out);
}

// Round 11
// 683.595 us; speedup vs baseline: 1.5721x; 1.1454x over previous
//
#include <hip/hip_runtime.h>
#include <math.h>

#define NN 100000
#define NE 1600000
#define NG 1000
#define BN_EPS 1e-5f
#define AGG_BLOCKS 2048
#define NWAVES (AGG_BLOCKS * 4)
#define CAP 512      // per-wave LDS index cache (ints)
#define RNG 500
#define NBUK 200
#define BB 512
#define BCAP 12288

typedef unsigned short ushort_t;
typedef unsigned int uint_t;
typedef __attribute__((ext_vector_type(8))) short bf16x8;
typedef __attribute__((ext_vector_type(4))) float f32x4;

__device__ inline float bf2f(ushort_t u) {
    return __uint_as_float(((uint_t)u) << 16);
}
__device__ inline ushort_t f2bf(float f) {
    uint_t u = __float_as_uint(f);
    u += 0x7FFFu + ((u >> 16) & 1u);   // RNE
    return (ushort_t)(u >> 16);
}

// ---------------- init ----------------

__global__ __launch_bounds__(256) void k_init(float* pooled, float* stats, int* bcnt) {
    int i = blockIdx.x * blockDim.x + threadIdx.x;
    int stride = gridDim.x * blockDim.x;
    for (int j = i; j < 5 * NG * 64; j += stride) pooled[j] = 0.f;
    for (int j = i; j < 1024; j += stride) stats[j] = 0.f;
    for (int j = i; j < NBUK; j += stride) bcnt[j] = 0;
}

__global__ __launch_bounds__(256) void k_f2bf(const float4* __restrict__ x, uint2* __restrict__ o) {
    int i = blockIdx.x * blockDim.x + threadIdx.x;
    int stride = gridDim.x * blockDim.x;
    for (int j = i; j < NN * 16; j += stride) {
        float4 v = x[j];
        uint2 r;
        r.x = (uint_t)f2bf(v.x) | ((uint_t)f2bf(v.y) << 16);
        r.y = (uint_t)f2bf(v.z) | ((uint_t)f2bf(v.w) << 16);
        o[j] = r;
    }
}

// ---------------- CSR build: block-local counting sort ----------------

__global__ __launch_bounds__(256) void k_cnt(const int* __restrict__ dst,
                                             int* __restrict__ cmat, int* __restrict__ bcnt) {
    __shared__ int l[NBUK];
    int b = blockIdx.x;
    for (int t = threadIdx.x; t < NBUK; t += 256) l[t] = 0;
    __syncthreads();
    int per = (NE + BB - 1) / BB;
    int s = b * per, e = min(NE, s + per);
    for (int i = s + threadIdx.x; i < e; i += 256) atomicAdd(&l[dst[i] / RNG], 1);
    __syncthreads();
    for (int t = threadIdx.x; t < NBUK; t += 256) {
        cmat[b * NBUK + t] = l[t];
        if (l[t]) atomicAdd(&bcnt[t], l[t]);
    }
}

__global__ __launch_bounds__(256) void k_boffscan(const int* __restrict__ bcnt,
                                                  const int* __restrict__ cmat,
                                                  int* __restrict__ wmat,
                                                  int* __restrict__ boff) {
    __shared__ int sb[256];
    __shared__ int s[256];
    int k = blockIdx.x;
    int t = threadIdx.x;
    int bv = (t < NBUK) ? bcnt[t] : 0;
    sb[t] = bv;
    __syncthreads();
    for (int o = 1; o < 256; o <<= 1) {
        int x = (t >= o) ? sb[t - o] : 0;
        __syncthreads();
        sb[t] += x;
        __syncthreads();
    }
    int boffk = sb[k] - ((k < NBUK) ? bcnt[k] : 0);
    if (t == 0) boff[k] = boffk;
    if (k == 0 && t == 0) boff[NBUK] = NE;
    int c0 = cmat[(2 * t) * NBUK + k];
    int c1 = cmat[(2 * t + 1) * NBUK + k];
    int sum = c0 + c1;
    s[t] = sum;
    __syncthreads();
    for (int o = 1; o < 256; o <<= 1) {
        int x = (t >= o) ? s[t - o] : 0;
        __syncthreads();
        s[t] += x;
        __syncthreads();
    }
    int excl = s[t] - sum + boffk;
    wmat[(2 * t) * NBUK + k] = excl;
    wmat[(2 * t + 1) * NBUK + k] = excl + c0;
}

__global__ __launch_bounds__(256) void k_bin2(const int* __restrict__ src, const int* __restrict__ dst,
                                              const int* __restrict__ wmat, uint_t* __restrict__ binned) {
    __shared__ int l[NBUK];
    int b = blockIdx.x;
    for (int t = threadIdx.x; t < NBUK; t += 256) l[t] = 0;
    __syncthreads();
    int per = (NE + BB - 1) / BB;
    int s = b * per, e = min(NE, s + per);
    for (int i = s + threadIdx.x; i < e; i += 256) {
        int d = dst[i];
        int k = d / RNG;
        int ldst = d - k * RNG;
        int r = atomicAdd(&l[k], 1);
        binned[wmat[b * NBUK + k] + r] = ((uint_t)ldst << 17) | (uint_t)src[i];
    }
}

__global__ __launch_bounds__(256) void k_bucket_finish(
    const uint_t* __restrict__ binned, const int* __restrict__ boff,
    int* __restrict__ off, int* __restrict__ csr)
{
    __shared__ uint_t ebuf[BCAP];
    __shared__ int cnt[512];
    __shared__ int a[256];
    __shared__ int wpos[RNG];
    int k = blockIdx.x;
    int t = threadIdx.x;
    int e0 = boff[k], e1 = boff[k + 1];
    int m = e1 - e0;
    bool inl = (m <= BCAP);

    cnt[t] = 0; cnt[t + 256] = 0;
    if (inl) for (int i = t; i < m; i += 256) ebuf[i] = binned[e0 + i];
    __syncthreads();
    for (int i = t; i < m; i += 256) {
        uint_t v = inl ? ebuf[i] : binned[e0 + i];
        atomicAdd(&cnt[v >> 17], 1);
    }
    __syncthreads();
    int c0 = cnt[2 * t], c1 = cnt[2 * t + 1];
    int sum = c0 + c1;
    a[t] = sum;
    __syncthreads();
    for (int o = 1; o < 256; o <<= 1) {
        int x = (t >= o) ? a[t - o] : 0;
        __syncthreads();
        a[t] += x;
        __syncthreads();
    }
    int excl = a[t] - sum;
    int base = k * RNG;
    if (2 * t < RNG) { off[base + 2 * t] = e0 + excl; wpos[2 * t] = excl; }
    if (2 * t + 1 < RNG) { off[base + 2 * t + 1] = e0 + excl + c0; wpos[2 * t + 1] = excl + c0; }
    if (k == NBUK - 1 && t == 0) off[NN] = NE;
    __syncthreads();
    for (int i = t; i < m; i += 256) {
        uint_t v = inl ? ebuf[i] : binned[e0 + i];
        int ldst = (int)(v >> 17);
        int r = atomicAdd(&wpos[ldst], 1);
        csr[e0 + r] = (int)(v & 0x1FFFFu);
    }
}

__global__ __launch_bounds__(256) void k_wstart(const int* __restrict__ off, int* __restrict__ wstart) {
    int w = blockIdx.x * blockDim.x + threadIdx.x;
    if (w > NWAVES) return;
    if (w == NWAVES) { wstart[w] = NN; return; }
    int t = (int)(((long long)w * NE) / NWAVES);
    int lo = 0, hi = NN;
    while (lo < hi) { int mid = (lo + hi) >> 1; if (off[mid] < t) lo = mid + 1; else hi = mid; }
    wstart[w] = lo;
}

// ---------------- k_agg: exact R6 version (108 us, VGPR 64) ----------------

template<int DORELU>
__global__ __launch_bounds__(256) void k_agg(
    const ushort_t* __restrict__ zb,
    const float* __restrict__ stats2p, const float* __restrict__ g2p, const float* __restrict__ b2p,
    const int* __restrict__ csr, const int* __restrict__ off, const int* __restrict__ wstart,
    const float* __restrict__ W1, ushort_t* __restrict__ yb,
    float* __restrict__ stats1,
    const int* __restrict__ gid, float* __restrict__ poolL)
{
    __shared__ __align__(16) float buf[4][64];
    __shared__ int sidx[4][CAP];
    __shared__ float sred[128];
    int lane = threadIdx.x & 63;
    int wslot = threadIdx.x >> 6;
    int wid = blockIdx.x * 4 + wslot;
    int fl = lane & 15;
    int grp = lane >> 4;

    float scv0 = 1.f, scv1 = 1.f, scv2 = 1.f, scv3 = 1.f;
    float shv0 = 0.f, shv1 = 0.f, shv2 = 0.f, shv3 = 0.f;
    if (DORELU) {
        int f = 4 * fl;
#define MKCO(q, scq, shq) { \
        float mean = stats2p[f + q] * (1.f / NN); \
        float var  = stats2p[64 + f + q] * (1.f / NN) - mean * mean; \
        scq = rsqrtf(var + BN_EPS) * g2p[f + q]; \
        shq = b2p[f + q] - mean * scq; }
        MKCO(0, scv0, shv0) MKCO(1, scv1, shv1) MKCO(2, scv2, shv2) MKCO(3, scv3, shv3)
#undef MKCO
    }

    float Wc[64];
#pragma unroll
    for (int k = 0; k < 64; k++) Wc[k] = W1[k * 64 + lane];

    float ls = 0.f, lss = 0.f;

    int n0 = wstart[wid], n1 = wstart[wid + 1];

    if (n0 < n1) {
        int e0 = off[n0];
        int eEnd = off[n1];
        int tot = eEnd - e0;
        int lim = min(tot, CAP);
        for (int t = lane; t < lim; t += 64) sidx[wslot][t] = csr[e0 + t];

        int curg = -1;
        float p0 = 0.f, p1 = 0.f, p2 = 0.f, p3 = 0.f;

#define AFF(t, scq, shq) (DORELU ? fmaxf(fmaf(t, scq, shq), 0.f) : (t))
#define UNPK(p, t0, t1, t2, t3) \
        float t0 = AFF(__uint_as_float(p.x << 16), scv0, shv0); \
        float t1 = AFF(__uint_as_float(p.x & 0xFFFF0000u), scv1, shv1); \
        float t2 = AFF(__uint_as_float(p.y << 16), scv2, shv2); \
        float t3 = AFF(__uint_as_float(p.y & 0xFFFF0000u), scv3, shv3);

        for (int n = n0; n < n1; ++n) {
            uint2 sp = *(const uint2*)(zb + ((size_t)n << 6) + (fl << 2));
            UNPK(sp, s0v, s1v, s2v, s3v)

            int g = gid[n];
            if (g != curg) {
                if (curg >= 0 && grp == 0) {
                    atomicAdd(&poolL[curg * 64 + 4 * fl], p0);
                    atomicAdd(&poolL[curg * 64 + 4 * fl + 1], p1);
                    atomicAdd(&poolL[curg * 64 + 4 * fl + 2], p2);
                    atomicAdd(&poolL[curg * 64 + 4 * fl + 3], p3);
                }
                curg = g; p0 = p1 = p2 = p3 = 0.f;
            }
            p0 += s0v; p1 += s1v; p2 += s2v; p3 += s3v;

            float b0 = 0.f, b1 = 0.f, b2 = 0.f, b3 = 0.f;
            int s0l = off[n] - e0, s1l = off[n + 1] - e0;
            int j = s0l + grp;
            if (s1l <= lim) {
                for (; j + 12 < s1l; j += 16) {
                    int i0 = sidx[wslot][j], i1 = sidx[wslot][j + 4],
                        i2 = sidx[wslot][j + 8], i3 = sidx[wslot][j + 12];
                    uint2 q0 = *(const uint2*)(zb + ((size_t)i0 << 6) + (fl << 2));
                    uint2 q1 = *(const uint2*)(zb + ((size_t)i1 << 6) + (fl << 2));
                    uint2 q2 = *(const uint2*)(zb + ((size_t)i2 << 6) + (fl << 2));
                    uint2 q3 = *(const uint2*)(zb + ((size_t)i3 << 6) + (fl << 2));
                    { UNPK(q0, t0, t1, t2, t3) b0 += t0; b1 += t1; b2 += t2; b3 += t3; }
                    { UNPK(q1, t0, t1, t2, t3) b0 += t0; b1 += t1; b2 += t2; b3 += t3; }
                    { UNPK(q2, t0, t1, t2, t3) b0 += t0; b1 += t1; b2 += t2; b3 += t3; }
                    { UNPK(q3, t0, t1, t2, t3) b0 += t0; b1 += t1; b2 += t2; b3 += t3; }
                }
                for (; j < s1l; j += 4) {
                    int i0 = sidx[wslot][j];
                    uint2 q0 = *(const uint2*)(zb + ((size_t)i0 << 6) + (fl << 2));
                    UNPK(q0, t0, t1, t2, t3) b0 += t0; b1 += t1; b2 += t2; b3 += t3;
                }
            } else {
                for (; j < s1l; j += 4) {
                    int i0 = csr[e0 + j];
                    uint2 q0 = *(const uint2*)(zb + ((size_t)i0 << 6) + (fl << 2));
                    UNPK(q0, t0, t1, t2, t3) b0 += t0; b1 += t1; b2 += t2; b3 += t3;
                }
            }
            b0 += __shfl_xor(b0, 16); b0 += __shfl_xor(b0, 32);
            b1 += __shfl_xor(b1, 16); b1 += __shfl_xor(b1, 32);
            b2 += __shfl_xor(b2, 16); b2 += __shfl_xor(b2, 32);
            b3 += __shfl_xor(b3, 16); b3 += __shfl_xor(b3, 32);

            if (grp == 0) {
                ((float4*)buf[wslot])[fl] = make_float4(s0v + b0, s1v + b1, s2v + b2, s3v + b3);
            }
            float yl = 0.f;
#pragma unroll
            for (int k = 0; k < 16; k++) {
                float4 z4 = *(const float4*)&buf[wslot][k * 4];
                yl = fmaf(z4.x, Wc[4 * k], yl);
                yl = fmaf(z4.y, Wc[4 * k + 1], yl);
                yl = fmaf(z4.z, Wc[4 * k + 2], yl);
                yl = fmaf(z4.w, Wc[4 * k + 3], yl);
            }
            yb[(size_t)n * 64 + lane] = f2bf(yl);
            ls += yl;
            lss += yl * yl;
        }
        if (curg >= 0 && grp == 0) {
            atomicAdd(&poolL[curg * 64 + 4 * fl], p0);
            atomicAdd(&poolL[curg * 64 + 4 * fl + 1], p1);
            atomicAdd(&poolL[curg * 64 + 4 * fl + 2], p2);
            atomicAdd(&poolL[curg * 64 + 4 * fl + 3], p3);
        }
#undef AFF
#undef UNPK
    }

    if (threadIdx.x < 128) sred[threadIdx.x] = 0.f;
    __syncthreads();
    atomicAdd(&sred[lane], ls);
    atomicAdd(&sred[64 + lane], lss);
    __syncthreads();
    if (threadIdx.x < 128) atomicAdd(&stats1[threadIdx.x], sred[threadIdx.x]);
}

// ---------------- k_g2m: MFMA version of BN1+ReLU+GEMM2+BN2stats ----------------
// One wave per 16-node batch. A = relu(bn1(y)) (16x64 bf16), B = W2 (64x64 bf16),
// D = z (16x64 f32). mfma_f32_16x16x32_bf16: A lane l -> row l&15, k (l>>4)*8+j;
// B lane l -> col l&15, k (l>>4)*8+j; D lane l -> col l&15, row (l>>4)*4+j (verified m89/m91).

__global__ __launch_bounds__(256) void k_g2m(
    const ushort_t* __restrict__ yb, const float* __restrict__ stats1,
    const float* __restrict__ g1, const float* __restrict__ b1,
    const float* __restrict__ W2, ushort_t* __restrict__ zb,
    float* __restrict__ stats2)
{
    __shared__ ushort_t zt[4][16][64];
    __shared__ float sred[128];
    int lane = threadIdx.x & 63;
    int wslot = threadIdx.x >> 6;
    int w = blockIdx.x * 4 + wslot;
    int r = lane & 15;
    int g = lane >> 4;

    if (threadIdx.x < 128) sred[threadIdx.x] = 0.f;
    __syncthreads();

    if (w < NN / 16) {
        int n0 = w * 16;

        // affine coefs for this lane's A features: g*8+e (lo) and 32+g*8+e (hi)
        float scL[8], shL[8], scH[8], shH[8];
#pragma unroll
        for (int e = 0; e < 8; e++) {
            int f = g * 8 + e;
            float mean = stats1[f] * (1.f / NN);
            float var  = stats1[64 + f] * (1.f / NN) - mean * mean;
            scL[e] = rsqrtf(var + BN_EPS) * g1[f];
            shL[e] = b1[f] - mean * scL[e];
            int f2 = 32 + f;
            float mean2 = stats1[f2] * (1.f / NN);
            float var2  = stats1[64 + f2] * (1.f / NN) - mean2 * mean2;
            scH[e] = rsqrtf(var2 + BN_EPS) * g1[f2];
            shH[e] = b1[f2] - mean2 * scH[e];
        }

        // B fragments: W2[k][col], col = c*16 + r, k = kstep*32 + g*8 + j
        bf16x8 B00, B01, B02, B03, B10, B11, B12, B13;
#pragma unroll
        for (int j = 0; j < 8; j++) {
            int k0 = (g * 8 + j) * 64;
            int k1 = (32 + g * 8 + j) * 64;
            B00[j] = (short)f2bf(W2[k0 + r]);
            B01[j] = (short)f2bf(W2[k0 + 16 + r]);
            B02[j] = (short)f2bf(W2[k0 + 32 + r]);
            B03[j] = (short)f2bf(W2[k0 + 48 + r]);
            B10[j] = (short)f2bf(W2[k1 + r]);
            B11[j] = (short)f2bf(W2[k1 + 16 + r]);
            B12[j] = (short)f2bf(W2[k1 + 32 + r]);
            B13[j] = (short)f2bf(W2[k1 + 48 + r]);
        }

        // A fragments: load row n0+r, features g*8.. and 32+g*8.., affine+relu, pack
        union { uint4 u; ushort_t s[8]; } a0u, a1u;
        a0u.u = *(const uint4*)(yb + (size_t)(n0 + r) * 64 + g * 8);
        a1u.u = *(const uint4*)(yb + (size_t)(n0 + r) * 64 + 32 + g * 8);
        bf16x8 A0, A1;
#pragma unroll
        for (int e = 0; e < 8; e++) {
            float v0 = fmaxf(fmaf(bf2f(a0u.s[e]), scL[e], shL[e]), 0.f);
            float v1 = fmaxf(fmaf(bf2f(a1u.s[e]), scH[e], shH[e]), 0.f);
            A0[e] = (short)f2bf(v0);
            A1[e] = (short)f2bf(v1);
        }

        f32x4 acc0 = {0.f, 0.f, 0.f, 0.f};
        f32x4 acc1 = acc0, acc2 = acc0, acc3 = acc0;
        acc0 = __builtin_amdgcn_mfma_f32_16x16x32_bf16(A0, B00, acc0, 0, 0, 0);
        acc1 = __builtin_amdgcn_mfma_f32_16x16x32_bf16(A0, B01, acc1, 0, 0, 0);
        acc2 = __builtin_amdgcn_mfma_f32_16x16x32_bf16(A0, B02, acc2, 0, 0, 0);
        acc3 = __builtin_amdgcn_mfma_f32_16x16x32_bf16(A0, B03, acc3, 0, 0, 0);
        acc0 = __builtin_amdgcn_mfma_f32_16x16x32_bf16(A1, B10, acc0, 0, 0, 0);
        acc1 = __builtin_amdgcn_mfma_f32_16x16x32_bf16(A1, B11, acc1, 0, 0, 0);
        acc2 = __builtin_amdgcn_mfma_f32_16x16x32_bf16(A1, B12, acc2, 0, 0, 0);
        acc3 = __builtin_amdgcn_mfma_f32_16x16x32_bf16(A1, B13, acc3, 0, 0, 0);

        // stats: lane holds z[rows (g)*4+j][col c*16+r]; sum over rows via xor16/32
        float ls0 = acc0.x + acc0.y + acc0.z + acc0.w;
        float ls1 = acc1.x + acc1.y + acc1.z + acc1.w;
        float ls2 = acc2.x + acc2.y + acc2.z + acc2.w;
        float ls3 = acc3.x + acc3.y + acc3.z + acc3.w;
        float lq0 = acc0.x * acc0.x + acc0.y * acc0.y + acc0.z * acc0.z + acc0.w * acc0.w;
        float lq1 = acc1.x * acc1.x + acc1.y * acc1.y + acc1.z * acc1.z + acc1.w * acc1.w;
        float lq2 = acc2.x * acc2.x + acc2.y * acc2.y + acc2.z * acc2.z + acc2.w * acc2.w;
        float lq3 = acc3.x * acc3.x + acc3.y * acc3.y + acc3.z * acc3.z + acc3.w * acc3.w;
        ls0 += __shfl_xor(ls0, 16); ls0 += __shfl_xor(ls0, 32);
        ls1 += __shfl_xor(ls1, 16); ls1 += __shfl_xor(ls1, 32);
        ls2 += __shfl_xor(ls2, 16); ls2 += __shfl_xor(ls2, 32);
        ls3 += __shfl_xor(ls3, 16); ls3 += __shfl_xor(ls3, 32);
        lq0 += __shfl_xor(lq0, 16); lq0 += __shfl_xor(lq0, 32);
        lq1 += __shfl_xor(lq1, 16); lq1 += __shfl_xor(lq1, 32);
        lq2 += __shfl_xor(lq2, 16); lq2 += __shfl_xor(lq2, 32);
        lq3 += __shfl_xor(lq3, 16); lq3 += __shfl_xor(lq3, 32);
        if (lane < 16) {
            atomicAdd(&sred[lane], ls0);
            atomicAdd(&sred[16 + lane], ls1);
            atomicAdd(&sred[32 + lane], ls2);
            atomicAdd(&sred[48 + lane], ls3);
            atomicAdd(&sred[64 + lane], lq0);
            atomicAdd(&sred[80 + lane], lq1);
            atomicAdd(&sred[96 + lane], lq2);
            atomicAdd(&sred[112 + lane], lq3);
        }

        // store: route through per-wave LDS transpose, then coalesced global
        zt[wslot][g * 4 + 0][r]      = f2bf(acc0.x);
        zt[wslot][g * 4 + 1][r]      = f2bf(acc0.y);
        zt[wslot][g * 4 + 2][r]      = f2bf(acc0.z);
        zt[wslot][g * 4 + 3][r]      = f2bf(acc0.w);
        zt[wslot][g * 4 + 0][16 + r] = f2bf(acc1.x);
        zt[wslot][g * 4 + 1][16 + r] = f2bf(acc1.y);
        zt[wslot][g * 4 + 2][16 + r] = f2bf(acc1.z);
        zt[wslot][g * 4 + 3][16 + r] = f2bf(acc1.w);
        zt[wslot][g * 4 + 0][32 + r] = f2bf(acc2.x);
        zt[wslot][g * 4 + 1][32 + r] = f2bf(acc2.y);
        zt[wslot][g * 4 + 2][32 + r] = f2bf(acc2.z);
        zt[wslot][g * 4 + 3][32 + r] = f2bf(acc2.w);
        zt[wslot][g * 4 + 0][48 + r] = f2bf(acc3.x);
        zt[wslot][g * 4 + 1][48 + r] = f2bf(acc3.y);
        zt[wslot][g * 4 + 2][48 + r] = f2bf(acc3.z);
        zt[wslot][g * 4 + 3][48 + r] = f2bf(acc3.w);

        int nl = lane >> 2;
        int c0 = (lane & 3) * 16;
        uint4 q0 = *(const uint4*)&zt[wslot][nl][c0];
        uint4 q1 = *(const uint4*)&zt[wslot][nl][c0 + 8];
        *(uint4*)(zb + (size_t)(n0 + nl) * 64 + c0) = q0;
        *(uint4*)(zb + (size_t)(n0 + nl) * 64 + c0 + 8) = q1;
    }

    __syncthreads();
    if (threadIdx.x < 128) atomicAdd(&stats2[threadIdx.x], sred[threadIdx.x]);
}

// ---------------- final hidden rep pooling (h_4) ----------------

__global__ __launch_bounds__(256) void k_pool4(
    const ushort_t* __restrict__ zb,
    const float* __restrict__ stats2, const float* __restrict__ g2, const float* __restrict__ b2,
    const int* __restrict__ gid, float* __restrict__ pool)
{
    int lane = threadIdx.x & 63;
    int wslot = threadIdx.x >> 6;
    int wid = blockIdx.x * 4 + wslot;
    int nw = gridDim.x * 4;
    int chunk = (NN + nw - 1) / nw;
    int n0 = wid * chunk, n1 = min(NN, n0 + chunk);
    if (n0 >= n1) return;

    float mean = stats2[lane] * (1.f / NN);
    float var  = stats2[64 + lane] * (1.f / NN) - mean * mean;
    float sc = rsqrtf(var + BN_EPS) * g2[lane];
    float sh = b2[lane] - mean * sc;

    int curg = -1;
    float pacc = 0.f;
    for (int n = n0; n < n1; ++n) {
        float v = fmaxf(fmaf(bf2f(zb[(size_t)n * 64 + lane]), sc, sh), 0.f);
        int g = gid[n];
        if (g != curg) {
            if (curg >= 0) atomicAdd(&pool[curg * 64 + lane], pacc);
            curg = g; pacc = 0.f;
        }
        pacc += v;
    }
    if (curg >= 0) atomicAdd(&pool[curg * 64 + lane], pacc);
}

// ---------------- epilogue ----------------

__global__ __launch_bounds__(256) void k_final(
    const float* __restrict__ pooled, const float* __restrict__ pW,
    const float* __restrict__ pb, float* __restrict__ out)
{
    int t = blockIdx.x * blockDim.x + threadIdx.x;
    int g = t >> 4;
    int c = t & 15;
    if (g >= NG) return;
    float acc = 0.f;
#pragma unroll
    for (int i = 0; i < 5; i++) {
        const float* P = pooled + (size_t)i * NG * 64 + g * 64;
        const float* W = pW + i * 64 * 16;
        float a = 0.f;
#pragma unroll
        for (int k = 0; k < 64; k++) a += P[k] * W[k * 16 + c];
        acc += a + pb[i * 16 + c];
    }
    float m = acc;
    for (int o = 1; o < 16; o <<= 1) m = fmaxf(m, __shfl_xor(m, o, 16));
    float e = expf(acc - m);
    float s = e;
    for (int o = 1; o < 16; o <<= 1) s += __shfl_xor(s, o, 16);
    out[g * 16 + c] = acc - m - logf(s);
}

// ---------------- launch ----------------

extern "C" void kernel_launch(void* const* d_in, const int* in_sizes, int n_in,
                              void* d_out, int out_size, void* d_ws, size_t ws_size,
                              hipStream_t stream) {
    const float* feat = (const float*)d_in[0];
    const float* W1   = (const float*)d_in[1];
    const float* W2   = (const float*)d_in[2];
    const float* bn1g = (const float*)d_in[3];
    const float* bn1b = (const float*)d_in[4];
    const float* bn2g = (const float*)d_in[5];
    const float* bn2b = (const float*)d_in[6];
    const float* pW   = (const float*)d_in[7];
    const float* pb   = (const float*)d_in[8];
    const int* src = (const int*)d_in[9];
    const int* dst = (const int*)d_in[10];
    const int* gid = (const int*)d_in[11];
    float* out = (float*)d_out;

    char* ws = (char*)d_ws;
    size_t o = 0;
    auto alloc = [&](size_t bytes) {
        void* p = ws + o;
        o += (bytes + 255) & ~(size_t)255;
        return p;
    };
    ushort_t* zb  = (ushort_t*)alloc((size_t)NN * 64 * 2);
    ushort_t* yb  = (ushort_t*)alloc((size_t)NN * 64 * 2);
    float* pooled = (float*)alloc((size_t)5 * NG * 64 * 4);
    float* stats  = (float*)alloc(1024 * 4);
    int* off  = (int*)alloc((size_t)(NN + 1) * 4);
    int* csr  = (int*)alloc((size_t)NE * 4);
    uint_t* binned = (uint_t*)alloc((size_t)NE * 4);
    int* cmat = (int*)alloc((size_t)BB * NBUK * 4);
    int* wmat = (int*)alloc((size_t)BB * NBUK * 4);
    int* bcnt = (int*)alloc(NBUK * 4);
    int* boff = (int*)alloc((NBUK + 1) * 4);
    int* wstart = (int*)alloc((NWAVES + 1) * 4);

    k_init<<<256, 256, 0, stream>>>(pooled, stats, bcnt);
    k_f2bf<<<1024, 256, 0, stream>>>((const float4*)feat, (uint2*)zb);
    k_cnt<<<BB, 256, 0, stream>>>(dst, cmat, bcnt);
    k_boffscan<<<NBUK, 256, 0, stream>>>(bcnt, cmat, wmat, boff);
    k_bin2<<<BB, 256, 0, stream>>>(src, dst, wmat, binned);
    k_bucket_finish<<<NBUK, 256, 0, stream>>>(binned, boff, off, csr);
    k_wstart<<<(NWAVES + 1 + 255) / 256, 256, 0, stream>>>(off, wstart);

    int g2m_blocks = (NN / 16 + 3) / 4;   // 1563
    for (int L = 0; L < 4; ++L) {
        float* s1 = stats + L * 256;
        float* s2 = s1 + 128;
        if (L == 0) {
            k_agg<0><<<AGG_BLOCKS, 256, 0, stream>>>(zb, nullptr, nullptr, nullptr,
                                                     csr, off, wstart, W1 + L * 4096, yb, s1,
                                                     gid, pooled + (size_t)L * NG * 64);
        } else {
            k_agg<1><<<AGG_BLOCKS, 256, 0, stream>>>(zb, stats + (L - 1) * 256 + 128,
                                                     bn2g + (L - 1) * 64, bn2b + (L - 1) * 64,
                                                     csr, off, wstart, W1 + L * 4096, yb, s1,
                                                     gid, pooled + (size_t)L * NG * 64);
        }
        k_g2m<<<g2m_blocks, 256, 0, stream>>>(yb, s1, bn1g + L * 64, bn1b + L * 64,
                                              W2 + L * 4096, zb, s2);
    }
    k_pool4<<<AGG_BLOCKS, 256, 0, stream>>>(zb, stats + 3 * 256 + 128, bn2g + 3 * 64, bn2b + 3 * 64,
                                            gid, pooled + (size_t)4 * NG * 64);
    k_final<<<(NG * 16 + 255) / 256, 256, 0, stream>>>(pooled, pW, pb, out);
}